// Round 9
// baseline (1160.261 us; speedup 1.0000x reference)
//
#include <hip/hip_runtime.h>
#include <hip/hip_cooperative_groups.h>
#include <math.h>

namespace cg = cooperative_groups;

#define HID 64
#define BSH 9          // 512 dst nodes per bucket
#define NPB 512
#define EPB 4096       // edges per block in bucket kernels

typedef __attribute__((ext_vector_type(8))) short bf16x8;
typedef __attribute__((ext_vector_type(4))) float f32x4;
typedef __attribute__((ext_vector_type(4))) unsigned int u32x4;

__device__ __forceinline__ unsigned short f2bf(float f) {
    unsigned u = __float_as_uint(f);
    unsigned r = u + 0x7FFF + ((u >> 16) & 1);  // RNE
    return (unsigned short)(r >> 16);
}
__device__ __forceinline__ float bf2f(unsigned short b) {
    return __uint_as_float(((unsigned)b) << 16);
}

struct Params {
    const float* x;
    const int* esrc;
    const int* edst;
    const float* W1; const float* a1s; const float* a1d; const float* b1;
    const float* W2; const float* a2s; const float* a2d; const float* b2;
    float* out;
    int* off; int* srcs; int2* ebuf;
    int* bcnt; int* bbase; int* bcur;
    unsigned short* h1; unsigned short* hB;
    float* as_; float* ad_;
    unsigned short* Wt1; unsigned short* Wt2;
    int N, E, NB, gbk, gblocks, ablocks;
};

union Smem {
    unsigned short xs[128 * 72];  // gemm X tile, 18432 B
    int i1280[1280];              // csr: dhist(512)+dbase(512)+psum(256); scatter: 768
};

// ---------------- phase bodies ----------------

__device__ void count_body(Smem& sm, const Params& P, int b) {
    int* hist = sm.i1280;
    int t = threadIdx.x;
    hist[t] = 0;
    __syncthreads();
    int base = b * EPB;
#pragma unroll
    for (int r = 0; r < EPB / 256; ++r) {
        int i = base + r * 256 + t;
        if (i < P.E) atomicAdd(&hist[P.edst[i] >> BSH], 1);
    }
    __syncthreads();
    if (t < P.NB && hist[t]) atomicAdd(&P.bcnt[t], hist[t]);
}

__device__ void wt_body(const float* W, unsigned short* Wt, int K, int wb) {
    int t = threadIdx.x;
    int k = wb * 4 + (t >> 6);
    int n = t & 63;
    if (k < K) Wt[(size_t)n * K + k] = f2bf(W[(size_t)k * 64 + n]);
}

__device__ void scan_body(Smem& sm, const Params& P) {
    int* sd = sm.i1280;
    int t = threadIdx.x;
    int v = (t < P.NB) ? P.bcnt[t] : 0;
    sd[t] = v;
    __syncthreads();
    for (int o = 1; o < 256; o <<= 1) {
        int u = (t >= o) ? sd[t - o] : 0;
        __syncthreads();
        sd[t] += u;
        __syncthreads();
    }
    int ex = sd[t] - v;
    if (t < P.NB) {
        P.bbase[t] = ex;
        P.bcur[t] = ex;
    }
    if (t == 0) P.bbase[P.NB] = sd[P.NB - 1];
}

__device__ void scatter_body(Smem& sm, const Params& P, int b) {
    int* hist = sm.i1280;
    int* chunk = hist + 256;
    int* lcur = chunk + 256;
    int t = threadIdx.x;
    hist[t] = 0;
    lcur[t] = 0;
    __syncthreads();
    int base = b * EPB;
    int s[EPB / 256], d[EPB / 256];
#pragma unroll
    for (int r = 0; r < EPB / 256; ++r) {
        int i = base + r * 256 + t;
        if (i < P.E) {
            s[r] = P.esrc[i];
            d[r] = P.edst[i];
            atomicAdd(&hist[d[r] >> BSH], 1);
        } else {
            d[r] = -1;
        }
    }
    __syncthreads();
    if (t < P.NB) chunk[t] = hist[t] ? atomicAdd(&P.bcur[t], hist[t]) : 0;
    __syncthreads();
#pragma unroll
    for (int r = 0; r < EPB / 256; ++r) {
        if (d[r] >= 0) {
            int bk = d[r] >> BSH;
            int pos = chunk[bk] + atomicAdd(&lcur[bk], 1);
            P.ebuf[pos] = make_int2(s[r], d[r]);
        }
    }
}

__device__ void csr_body(Smem& sm, const Params& P, int b) {
    int* dhist = sm.i1280;
    int* dbase = dhist + NPB;
    int* psum = dbase + NPB;
    int t = threadIdx.x;
    int e0 = P.bbase[b], e1 = P.bbase[b + 1];
#pragma unroll
    for (int j = t; j < NPB; j += 256) dhist[j] = 0;
    __syncthreads();
    for (int i = e0 + t; i < e1; i += 256) {
        int d = P.ebuf[i].y;
        atomicAdd(&dhist[d & (NPB - 1)], 1);
    }
    __syncthreads();
    int a0 = dhist[2 * t], a1 = dhist[2 * t + 1];
    psum[t] = a0 + a1;
    __syncthreads();
    for (int o = 1; o < 256; o <<= 1) {
        int u = (t >= o) ? psum[t - o] : 0;
        __syncthreads();
        psum[t] += u;
        __syncthreads();
    }
    int ex = psum[t] - (a0 + a1);
    dbase[2 * t] = ex;
    dbase[2 * t + 1] = ex + a0;
    __syncthreads();
    for (int j = t; j < NPB; j += 256) {
        int node = (b << BSH) + j;
        if (node < P.N) P.off[node] = e0 + dbase[j];
    }
    if (b == P.NB - 1 && t == 0) P.off[P.N] = e1;
    __syncthreads();
    for (int i = e0 + t; i < e1; i += 256) {
        int2 p = P.ebuf[i];
        int pos = atomicAdd(&dbase[p.y & (NPB - 1)], 1);
        P.srcs[e0 + pos] = p.x;
    }
}

// MFMA GEMM tile + fused attention dots. W from global (L1/L2-hot, 32 KB).
template <int K, bool BF16IN>
__device__ void gemm_body(Smem& sm, int tile, const void* __restrict__ Xv,
                          const unsigned short* __restrict__ Wt,
                          const float* __restrict__ a_s, const float* __restrict__ a_d,
                          unsigned short* __restrict__ C, float* __restrict__ as_,
                          float* __restrict__ ad_, int Nrows) {
    constexpr int XPAD = 72;
    unsigned short* Xs = sm.xs;

    const float* Xf = (const float*)Xv;
    const unsigned short* Xb = (const unsigned short*)Xv;

    int t = threadIdx.x;
    int n0 = tile * 128;
    int lane = t & 63;
    int w = t >> 6;
    int m = lane & 15;
    int q = lane >> 4;
    int base = n0 + w * 32;

    f32x4 acc[2][4];
#pragma unroll
    for (int mi = 0; mi < 2; ++mi)
#pragma unroll
        for (int ct = 0; ct < 4; ++ct) acc[mi][ct] = (f32x4){0.f, 0.f, 0.f, 0.f};

    for (int k0 = 0; k0 < K; k0 += 64) {
        if (!BF16IN) {
#pragma unroll
            for (int i = 0; i < 8; ++i) {
                int idx = i * 256 + t;
                int row = idx >> 4;
                int kq = (idx & 15) * 4;
                int gn = n0 + row;
                if (gn >= Nrows) gn = Nrows - 1;
                float4 v = *(const float4*)(Xf + (size_t)gn * K + k0 + kq);
                ushort4 bb;
                bb.x = f2bf(v.x); bb.y = f2bf(v.y); bb.z = f2bf(v.z); bb.w = f2bf(v.w);
                *(ushort4*)(&Xs[row * XPAD + kq]) = bb;
            }
        } else {
#pragma unroll
            for (int i = 0; i < 4; ++i) {
                int idx = i * 256 + t;
                int row = idx >> 3;
                int kq = (idx & 7) * 8;
                int gn = n0 + row;
                if (gn >= Nrows) gn = Nrows - 1;
                u32x4 v = *(const u32x4*)(Xb + (size_t)gn * K + k0 + kq);
                *(u32x4*)(&Xs[row * XPAD + kq]) = v;
            }
        }
        __syncthreads();
#pragma unroll
        for (int ks = 0; ks < 64; ks += 32) {
            bf16x8 a0 = *(const bf16x8*)(&Xs[(w * 32 + m) * XPAD + ks + q * 8]);
            bf16x8 a1 = *(const bf16x8*)(&Xs[(w * 32 + 16 + m) * XPAD + ks + q * 8]);
#pragma unroll
            for (int ct = 0; ct < 4; ++ct) {
                bf16x8 bv = *(const bf16x8*)(Wt + (size_t)(ct * 16 + m) * K + k0 + ks + q * 8);
                acc[0][ct] = __builtin_amdgcn_mfma_f32_16x16x32_bf16(a0, bv, acc[0][ct], 0, 0, 0);
                acc[1][ct] = __builtin_amdgcn_mfma_f32_16x16x32_bf16(a1, bv, acc[1][ct], 0, 0, 0);
            }
        }
        __syncthreads();
    }

    float sa0 = a_s[m], sa1 = a_s[16 + m], sa2 = a_s[32 + m], sa3 = a_s[48 + m];
    float da0 = a_d[m], da1 = a_d[16 + m], da2 = a_d[32 + m], da3 = a_d[48 + m];

#pragma unroll
    for (int mi = 0; mi < 2; ++mi) {
#pragma unroll
        for (int r = 0; r < 4; ++r) {
            int row = base + mi * 16 + q * 4 + r;
            if (row < Nrows) {
                size_t ro = (size_t)row * 64 + m;
                C[ro]      = f2bf(acc[mi][0][r]);
                C[ro + 16] = f2bf(acc[mi][1][r]);
                C[ro + 32] = f2bf(acc[mi][2][r]);
                C[ro + 48] = f2bf(acc[mi][3][r]);
            }
        }
        float vs[4], vd[4];
#pragma unroll
        for (int r = 0; r < 4; ++r) {
            float s = acc[mi][0][r] * sa0 + acc[mi][1][r] * sa1 +
                      acc[mi][2][r] * sa2 + acc[mi][3][r] * sa3;
            float d = acc[mi][0][r] * da0 + acc[mi][1][r] * da1 +
                      acc[mi][2][r] * da2 + acc[mi][3][r] * da3;
#pragma unroll
            for (int o = 1; o < 16; o <<= 1) {
                s += __shfl_xor(s, o);
                d += __shfl_xor(d, o);
            }
            vs[r] = s;
            vd[r] = d;
        }
        if (m < 4) {
            int row = base + mi * 16 + q * 4 + m;
            float wvs = (m == 0) ? vs[0] : (m == 1) ? vs[1] : (m == 2) ? vs[2] : vs[3];
            float wvd = (m == 0) ? vd[0] : (m == 1) ? vd[1] : (m == 2) ? vd[2] : vd[3];
            if (row < Nrows) {
                as_[row] = wvs;
                ad_[row] = wvd;
            }
        }
    }
}

// aggregation: one wave per node; coalesced 4-row gather (no LDS, no block sync)
template <bool RELU_BF16OUT>
__device__ void agg_body(const unsigned short* __restrict__ H,
                         const float* __restrict__ as_, const float* __restrict__ ad_,
                         const float* __restrict__ bias, const int* __restrict__ off,
                         const int* __restrict__ srcs, void* __restrict__ outp,
                         int d4, int Nrows) {
    int d = d4 * 4 + (threadIdx.x >> 6);
    int lane = threadIdx.x & 63;
    if (d >= Nrows) return;
    int begin = off[d], end = off[d + 1];
    float adv = ad_[d];
    int g = lane >> 4;
    int c4 = (lane & 15) * 4;
    float4 acc = {0.f, 0.f, 0.f, 0.f};
    float lsum = 0.f;

    for (int bbase = begin; bbase < end; bbase += 64) {
        int cnt = end - bbase;
        if (cnt > 64) cnt = 64;
        int s = 0;
        float p = 0.f;
        if (lane < cnt) {
            s = srcs[bbase + lane];
            float xv = as_[s] + adv;
            xv = (xv > 0.f) ? xv : 0.2f * xv;  // leaky_relu 0.2
            p = __expf(xv);
        }
        lsum += p;
        int nb = (cnt + 3) & ~3;
        for (int j = 0; j < nb; j += 4) {
            int sv = __shfl(s, j + g);
            float pv = __shfl(p, j + g);
            ushort4 hv = *(const ushort4*)(H + (size_t)sv * HID + c4);
            acc.x += pv * bf2f(hv.x);
            acc.y += pv * bf2f(hv.y);
            acc.z += pv * bf2f(hv.z);
            acc.w += pv * bf2f(hv.w);
        }
    }
#pragma unroll
    for (int o = 16; o <= 32; o <<= 1) {
        acc.x += __shfl_xor(acc.x, o);
        acc.y += __shfl_xor(acc.y, o);
        acc.z += __shfl_xor(acc.z, o);
        acc.w += __shfl_xor(acc.w, o);
    }
#pragma unroll
    for (int o = 32; o; o >>= 1) lsum += __shfl_xor(lsum, o);
    if (g == 0) {
        float inv = 1.f / (lsum + 1e-16f);
        float4 b4 = *(const float4*)(bias + c4);
        float o0 = acc.x * inv + b4.x;
        float o1 = acc.y * inv + b4.y;
        float o2 = acc.z * inv + b4.z;
        float o3 = acc.w * inv + b4.w;
        if (RELU_BF16OUT) {
            ushort4 ov;
            ov.x = f2bf(fmaxf(o0, 0.f));
            ov.y = f2bf(fmaxf(o1, 0.f));
            ov.z = f2bf(fmaxf(o2, 0.f));
            ov.w = f2bf(fmaxf(o3, 0.f));
            *(ushort4*)((unsigned short*)outp + (size_t)d * HID + c4) = ov;
        } else {
            *(float4*)((float*)outp + (size_t)d * HID + c4) = make_float4(o0, o1, o2, o3);
        }
    }
}

// ---------------- mega kernel (grid-size agnostic, grid-stride phases) ----------------

__global__ __launch_bounds__(256, 4) void mega_kernel(Params P) {
    cg::grid_group grid = cg::this_grid();
    __shared__ Smem sm;
    int b = blockIdx.x;
    int G = gridDim.x;

    // A: bucket_count || wt1 || wt2
    int itemsA = P.gbk + 64 + 16;
    for (int i = b; i < itemsA; i += G) {
        if (i < P.gbk) count_body(sm, P, i);
        else if (i < P.gbk + 64) wt_body(P.W1, P.Wt1, 256, i - P.gbk);
        else wt_body(P.W2, P.Wt2, 64, i - P.gbk - 64);
        __syncthreads();
    }
    __threadfence();
    grid.sync();

    // B: scan
    if (b == 0) scan_body(sm, P);
    __threadfence();
    grid.sync();

    // C: scatter (first gbk items) || gemm1 tiles
    int itemsC = P.gbk + P.gblocks;
    for (int i = b; i < itemsC; i += G) {
        if (i < P.gbk)
            scatter_body(sm, P, i);
        else
            gemm_body<256, false>(sm, i - P.gbk, P.x, P.Wt1, P.a1s, P.a1d,
                                  P.h1, P.as_, P.ad_, P.N);
        __syncthreads();
    }
    __threadfence();
    grid.sync();

    // D: csr_build
    for (int i = b; i < P.NB; i += G) {
        csr_body(sm, P, i);
        __syncthreads();
    }
    __threadfence();
    grid.sync();

    // E: agg1 (h1 -> hB, relu+bf16)
    for (int d4 = b; d4 < P.ablocks; d4 += G)
        agg_body<true>(P.h1, P.as_, P.ad_, P.b1, P.off, P.srcs, P.hB, d4, P.N);
    __threadfence();
    grid.sync();

    // F: gemm2 (hB -> h1)
    for (int tile = b; tile < P.gblocks; tile += G) {
        gemm_body<64, true>(sm, tile, P.hB, P.Wt2, P.a2s, P.a2d, P.h1, P.as_, P.ad_, P.N);
        __syncthreads();
    }
    __threadfence();
    grid.sync();

    // G: agg2 (h1 -> out, fp32)
    for (int d4 = b; d4 < P.ablocks; d4 += G)
        agg_body<false>(P.h1, P.as_, P.ad_, P.b2, P.off, P.srcs, P.out, d4, P.N);
}

// ---------------- standalone fallback kernels (round-7 structure) ----------------

__global__ __launch_bounds__(256) void k_countwt(Params P) {
    __shared__ Smem sm;
    int b = blockIdx.x;
    if (b < P.gbk) count_body(sm, P, b);
    else if (b < P.gbk + 64) wt_body(P.W1, P.Wt1, 256, b - P.gbk);
    else wt_body(P.W2, P.Wt2, 64, b - P.gbk - 64);
}
__global__ __launch_bounds__(256) void k_scan(Params P) {
    __shared__ Smem sm;
    scan_body(sm, P);
}
__global__ __launch_bounds__(256) void k_scatter(Params P) {
    __shared__ Smem sm;
    scatter_body(sm, P, blockIdx.x);
}
__global__ __launch_bounds__(256) void k_csr(Params P) {
    __shared__ Smem sm;
    csr_body(sm, P, blockIdx.x);
}
__global__ __launch_bounds__(256, 4) void k_gemm1(Params P) {
    __shared__ Smem sm;
    gemm_body<256, false>(sm, blockIdx.x, P.x, P.Wt1, P.a1s, P.a1d, P.h1, P.as_, P.ad_, P.N);
}
__global__ __launch_bounds__(256, 4) void k_gemm2(Params P) {
    __shared__ Smem sm;
    gemm_body<64, true>(sm, blockIdx.x, P.hB, P.Wt2, P.a2s, P.a2d, P.h1, P.as_, P.ad_, P.N);
}
__global__ __launch_bounds__(256) void k_agg1(Params P) {
    agg_body<true>(P.h1, P.as_, P.ad_, P.b1, P.off, P.srcs, P.hB, blockIdx.x, P.N);
}
__global__ __launch_bounds__(256) void k_agg2(Params P) {
    agg_body<false>(P.h1, P.as_, P.ad_, P.b2, P.off, P.srcs, P.out, blockIdx.x, P.N);
}

// ---------------- launch ----------------

extern "C" void kernel_launch(void* const* d_in, const int* in_sizes, int n_in,
                              void* d_out, int out_size, void* d_ws, size_t ws_size,
                              hipStream_t stream) {
    const int N = in_sizes[0] / 256;  // 100000
    const int E = in_sizes[1] / 2;    // 1000000
    const int IN_C = 256;
    const int NB = (N + NPB - 1) >> BSH;  // 196

    char* w = (char*)d_ws;
    auto alloc = [&](size_t bytes) {
        char* p = w;
        w += (bytes + 255) & ~(size_t)255;
        return p;
    };

    Params P;
    P.x    = (const float*)d_in[0];
    P.esrc = (const int*)d_in[1];
    P.edst = (const int*)d_in[1] + E;
    P.W1  = (const float*)d_in[2];
    P.a1s = (const float*)d_in[3];
    P.a1d = (const float*)d_in[4];
    P.b1  = (const float*)d_in[5];
    P.W2  = (const float*)d_in[6];
    P.a2s = (const float*)d_in[7];
    P.a2d = (const float*)d_in[8];
    P.b2  = (const float*)d_in[9];
    P.out = (float*)d_out;

    P.off   = (int*)alloc((size_t)(N + 1) * 4);
    P.srcs  = (int*)alloc((size_t)E * 4);
    P.ebuf  = (int2*)alloc((size_t)E * 8);
    P.bcnt  = (int*)alloc(256 * 4);
    P.bbase = (int*)alloc(257 * 4);
    P.bcur  = (int*)alloc(256 * 4);
    P.h1    = (unsigned short*)alloc((size_t)N * HID * 2);
    P.hB    = (unsigned short*)alloc((size_t)N * HID * 2);
    P.as_   = (float*)alloc((size_t)N * 4);
    P.ad_   = (float*)alloc((size_t)N * 4);
    P.Wt1   = (unsigned short*)alloc((size_t)IN_C * 64 * 2);
    P.Wt2   = (unsigned short*)alloc((size_t)64 * 64 * 2);

    P.N = N;
    P.E = E;
    P.NB = NB;
    P.gbk = (E + EPB - 1) / EPB;       // 245
    P.gblocks = (N + 127) / 128;       // 782
    P.ablocks = (N + 3) / 4;           // 25000

    hipMemsetAsync(P.bcnt, 0, 256 * 4, stream);

    // query actual co-residency (capture-safe host queries, deterministic)
    int dev = 0;
    hipGetDevice(&dev);
    int numCU = 256;
    hipDeviceGetAttribute(&numCU, hipDeviceAttributeMultiprocessorCount, dev);
    int maxb = 0;
    hipOccupancyMaxActiveBlocksPerMultiprocessor(&maxb, (const void*)mega_kernel, 256, 0);
    long Gl = (long)maxb * (long)numCU;
    int G = (Gl > 1024) ? 1024 : (int)Gl;

    bool ok = false;
    if (G >= 256) {
        void* args[] = {(void*)&P};
        hipError_t err = hipLaunchCooperativeKernel((const void*)mega_kernel, dim3(G),
                                                    dim3(256), args, 0, stream);
        ok = (err == hipSuccess);
    }
    if (!ok) {
        // fallback: proven 8-dispatch sequence (round 7)
        k_countwt<<<P.gbk + 80, 256, 0, stream>>>(P);
        k_scan<<<1, 256, 0, stream>>>(P);
        k_scatter<<<P.gbk, 256, 0, stream>>>(P);
        k_csr<<<NB, 256, 0, stream>>>(P);
        k_gemm1<<<P.gblocks, 256, 0, stream>>>(P);
        k_agg1<<<P.ablocks, 256, 0, stream>>>(P);
        k_gemm2<<<P.gblocks, 256, 0, stream>>>(P);
        k_agg2<<<P.ablocks, 256, 0, stream>>>(P);
    }
}